// Round 3
// baseline (475.854 us; speedup 1.0000x reference)
//
#include <hip/hip_runtime.h>

#define B_  4
#define C_  512
#define CQ_ 64
#define N_  4096

typedef _Float16 half8 __attribute__((ext_vector_type(8)));
typedef float    f32x4 __attribute__((ext_vector_type(4)));

// ---------------------------------------------------------------------------
// Kernel 1: fused QKV projection (unchanged from round 2).
// Q, K stored n-major: Qh[b][n][cq];  V stored d-major: Vh[b][d][m]
// ---------------------------------------------------------------------------
__global__ __launch_bounds__(256) void proj_kernel(
    const float* __restrict__ x,  const float* __restrict__ Wq,
    const float* __restrict__ Wk, const float* __restrict__ Wv,
    _Float16* __restrict__ Qh, _Float16* __restrict__ Kh, _Float16* __restrict__ Vh)
{
  __shared__ _Float16 As[64][40];
  __shared__ _Float16 Bs[64][40];

  const int tid = threadIdx.x;
  const int wid = tid >> 6, lane = tid & 63, ln = lane & 15, lh = lane >> 4;
  const int nBase  = blockIdx.x * 64;
  const int chTile = blockIdx.y;
  const int b      = blockIdx.z;

  const float* Wsrc;
  if (chTile == 0)      Wsrc = Wq;
  else if (chTile == 1) Wsrc = Wk;
  else                  Wsrc = Wv + (size_t)(chTile - 2) * 64 * C_;

  f32x4 acc[4] = {};

  const int ar = tid >> 2, ac = (tid & 3) * 8;
  const int bc = tid >> 3, bn = (tid & 7) * 8;

  for (int kt = 0; kt < C_; kt += 32) {
    __syncthreads();
    {
      const float* src = Wsrc + (size_t)ar * C_ + kt + ac;
      #pragma unroll
      for (int u = 0; u < 8; ++u) As[ar][ac + u] = (_Float16)src[u];
    }
    {
      const float* src = x + ((size_t)b * C_ + kt + bc) * N_ + nBase + bn;
      #pragma unroll
      for (int u = 0; u < 8; ++u) Bs[bn + u][bc] = (_Float16)src[u];
    }
    __syncthreads();
    half8 a = *(const half8*)&As[wid * 16 + ln][lh * 8];
    #pragma unroll
    for (int ct = 0; ct < 4; ++ct) {
      half8 bf = *(const half8*)&Bs[ct * 16 + ln][lh * 8];
      acc[ct] = __builtin_amdgcn_mfma_f32_16x16x32_f16(a, bf, acc[ct], 0, 0, 0);
    }
  }

  #pragma unroll
  for (int ct = 0; ct < 4; ++ct) {
    const int n = nBase + ct * 16 + ln;
    #pragma unroll
    for (int j = 0; j < 4; ++j) {
      const int chL = wid * 16 + lh * 4 + j;
      const _Float16 v = (_Float16)acc[ct][j];
      if (chTile == 0)      Qh[((size_t)b * N_ + n) * CQ_ + chL] = v;
      else if (chTile == 1) Kh[((size_t)b * N_ + n) * CQ_ + chL] = v;
      else                  Vh[((size_t)b * C_ + (chTile - 2) * 64 + chL) * N_ + n] = v;
    }
  }
}

// ---------------------------------------------------------------------------
// Kernel 2: softmax stats. Block = (b, 64 rows), 4 waves; wave w owns 16 rows.
// Computes exact row max m and inverse denom 1/l over all 4096 keys.
// K staged through double-buffered swizzled LDS; one barrier per 64-key chunk.
// ---------------------------------------------------------------------------
__global__ __launch_bounds__(256) void stats_kernel(
    const _Float16* __restrict__ Qh, const _Float16* __restrict__ Kh,
    float* __restrict__ m_g, float* __restrict__ il_g)
{
  __shared__ _Float16 Ks[2][64][64];   // 16 KB, col-swizzled: col ^= (row&7)<<3
  _Float16* ks = &Ks[0][0][0];

  const int tid = threadIdx.x;
  const int wid = tid >> 6, lane = tid & 63, ln = lane & 15, lh = lane >> 4;
  const int b  = blockIdx.x >> 6;
  const int n0 = (blockIdx.x & 63) * 64;

  const size_t qrow = ((size_t)b * N_ + n0 + wid * 16 + ln) * CQ_;
  half8 qf0 = *(const half8*)&Qh[qrow + lh * 8];
  half8 qf1 = *(const half8*)&Qh[qrow + 32 + lh * 8];

  const _Float16* Kb = Kh + (size_t)b * N_ * CQ_;

  // staging geometry: 8192B per chunk, 2x16B per thread (linear global read,
  // swizzled LDS write)
  const int s0 = tid * 16, s1 = tid * 16 + 4096;
  const int r0 = s0 >> 7, c0 = (s0 >> 4) & 7;
  const int r1 = s1 >> 7, c1 = (s1 >> 4) & 7;
  const int g0 = r0 * 64 + c0 * 8,  g1 = r1 * 64 + c1 * 8;       // halfs
  const int d0 = r0 * 64 + ((c0 ^ (r0 & 7)) << 3);
  const int d1 = r1 * 64 + ((c1 ^ (r1 & 7)) << 3);

  float mx[4] = {-3.0e38f, -3.0e38f, -3.0e38f, -3.0e38f};
  float sm[4] = {0.f, 0.f, 0.f, 0.f};

  {  // prologue: stage chunk 0
    f32x4 t0 = *(const f32x4*)&Kb[g0];
    f32x4 t1 = *(const f32x4*)&Kb[g1];
    *(f32x4*)(ks + d0) = t0;
    *(f32x4*)(ks + d1) = t1;
  }
  __syncthreads();

  for (int it = 0; it < 64; ++it) {
    const int buf = it & 1;
    f32x4 t0, t1;
    if (it < 63) {
      const size_t base = (size_t)(it + 1) * 64 * 64;
      t0 = *(const f32x4*)&Kb[base + g0];
      t1 = *(const f32x4*)&Kb[base + g1];
    }
    const int sw = (ln & 7) << 3;
    #pragma unroll
    for (int ct = 0; ct < 4; ++ct) {
      const int row = ct * 16 + ln;
      half8 k0 = *(const half8*)(ks + buf * 4096 + row * 64 + ((lh * 8) ^ sw));
      half8 k1 = *(const half8*)(ks + buf * 4096 + row * 64 + ((32 + lh * 8) ^ sw));
      f32x4 e = {};
      e = __builtin_amdgcn_mfma_f32_16x16x32_f16(qf0, k0, e, 0, 0, 0);
      e = __builtin_amdgcn_mfma_f32_16x16x32_f16(qf1, k1, e, 0, 0, 0);
      #pragma unroll
      for (int j = 0; j < 4; ++j) {
        const float v = e[j];
        const float mo = mx[j];
        const float mn = fmaxf(mo, v);
        sm[j] = sm[j] * __expf(mo - mn) + __expf(v - mn);
        mx[j] = mn;
      }
    }
    if (it < 63) {
      *(f32x4*)(ks + (buf ^ 1) * 4096 + d0) = t0;
      *(f32x4*)(ks + (buf ^ 1) * 4096 + d1) = t1;
    }
    __syncthreads();
  }

  // cross-lane merge over ln (16 lanes share the same 4 rows per lh group)
  #pragma unroll
  for (int j = 0; j < 4; ++j) {
    float m = mx[j], s = sm[j];
    #pragma unroll
    for (int mask = 1; mask <= 8; mask <<= 1) {
      const float om = __shfl_xor(m, mask);
      const float os = __shfl_xor(s, mask);
      const float mn = fmaxf(m, om);
      s = s * __expf(m - mn) + os * __expf(om - mn);
      m = mn;
    }
    if (ln == 0) {
      const int row = n0 + wid * 16 + lh * 4 + j;
      m_g[(size_t)b * N_ + row]  = m;
      il_g[(size_t)b * N_ + row] = 1.0f / s;
    }
  }
}

// ---------------------------------------------------------------------------
// Kernel 3: PV pass with known stats. Block = (b, d-half, 32 rows), 4 waves,
// wave owns 64 d. Per iter (128 keys): P computed in regs -> swizzled fp16
// LDS -> PV MFMA. ONE barrier per iter (double-buffered Ps). K prefetched one
// iter ahead; dt0's V prefetched during phase 1.
// ---------------------------------------------------------------------------
__global__ __launch_bounds__(256, 4) void flashb_kernel(
    const float* __restrict__ x, const _Float16* __restrict__ Qh,
    const _Float16* __restrict__ Kh, const _Float16* __restrict__ Vh,
    const float* __restrict__ m_g, const float* __restrict__ il_g,
    const float* __restrict__ gamma, float* __restrict__ out)
{
  __shared__ _Float16 Ps[2][32][128];   // 16 KB, col-swizzled: col ^= (n&7)<<3
  __shared__ float m_l[32], il_l[32];

  const int tid = threadIdx.x;
  const int wid = tid >> 6, lane = tid & 63, ln = lane & 15, lh = lane >> 4;

  // bijective XCD swizzle: 1024 blocks, 128 consecutive wg (one b,d-half) per XCD
  const int wg = ((blockIdx.x & 7) << 7) + (blockIdx.x >> 3);
  const int b  = wg >> 8;
  const int dh = (wg >> 7) & 1;
  const int n0 = (wg & 127) * 32;
  const int d0 = dh * 256 + wid * 64;

  if (tid < 32) {
    m_l[tid]  = m_g[(size_t)b * N_ + n0 + tid];
    il_l[tid] = il_g[(size_t)b * N_ + n0 + tid];
  }

  // Q fragments (32 rows), persistent
  half8 qf[2][2];
  #pragma unroll
  for (int rt = 0; rt < 2; ++rt)
    #pragma unroll
    for (int kk = 0; kk < 2; ++kk)
      qf[rt][kk] = *(const half8*)&Qh[((size_t)b * N_ + n0 + rt * 16 + ln) * CQ_ + kk * 32 + lh * 8];

  // K frags for it=0 (wave covers cols wid*32 .. wid*32+32)
  half8 kf[2][2];
  #pragma unroll
  for (int cg = 0; cg < 2; ++cg)
    #pragma unroll
    for (int kk = 0; kk < 2; ++kk)
      kf[cg][kk] = *(const half8*)&Kh[((size_t)b * N_ + (wid << 5) + cg * 16 + ln) * CQ_ + kk * 32 + lh * 8];

  f32x4 acc[4][2] = {};
  const _Float16* vbase = Vh + ((size_t)b * C_ + d0 + ln) * (size_t)N_ + lh * 8;

  __syncthreads();

  for (int it = 0; it < 32; ++it) {
    const int m0  = it << 7;
    const int cur = it & 1;

    // prefetch next iter's K
    half8 kn[2][2];
    if (it < 31) {
      #pragma unroll
      for (int cg = 0; cg < 2; ++cg)
        #pragma unroll
        for (int kk = 0; kk < 2; ++kk)
          kn[cg][kk] = *(const half8*)&Kh[((size_t)b * N_ + m0 + 128 + (wid << 5) + cg * 16 + ln) * CQ_ + kk * 32 + lh * 8];
    }
    // prefetch this iter's dt=0 V tile
    const _Float16* vp = vbase + m0;
    half8 vp0 = *(const half8*)(vp);
    half8 vp1 = *(const half8*)(vp + 32);
    half8 vp2 = *(const half8*)(vp + 64);
    half8 vp3 = *(const half8*)(vp + 96);

    // ---- Phase 1: E in regs -> P = exp(e-m)/l -> swizzled fp16 LDS
    #pragma unroll
    for (int cg = 0; cg < 2; ++cg) {
      #pragma unroll
      for (int rt = 0; rt < 2; ++rt) {
        f32x4 e = {};
        e = __builtin_amdgcn_mfma_f32_16x16x32_f16(qf[rt][0], kf[cg][0], e, 0, 0, 0);
        e = __builtin_amdgcn_mfma_f32_16x16x32_f16(qf[rt][1], kf[cg][1], e, 0, 0, 0);
        #pragma unroll
        for (int j = 0; j < 4; ++j) {
          const int n = rt * 16 + lh * 4 + j;
          const float p = __expf(e[j] - m_l[n]) * il_l[n];
          const int c = (wid << 5) + (cg << 4) + ln;
          Ps[cur][n][c ^ ((n & 7) << 3)] = (_Float16)p;
        }
      }
    }
    if (it < 31) {
      #pragma unroll
      for (int cg = 0; cg < 2; ++cg)
        #pragma unroll
        for (int kk = 0; kk < 2; ++kk)
          kf[cg][kk] = kn[cg][kk];
    }
    __syncthreads();

    // ---- Phase 2: PV MFMA
    half8 pf[2][4];
    const int swr = (ln & 7) << 3;
    #pragma unroll
    for (int nt = 0; nt < 2; ++nt)
      #pragma unroll
      for (int q = 0; q < 4; ++q)
        pf[nt][q] = *(const half8*)&Ps[cur][nt * 16 + ln][(q * 32 + lh * 8) ^ swr];

    __builtin_amdgcn_s_setprio(1);
    #pragma unroll
    for (int nt = 0; nt < 2; ++nt) {
      f32x4 a = acc[0][nt];
      a = __builtin_amdgcn_mfma_f32_16x16x32_f16(vp0, pf[nt][0], a, 0, 0, 0);
      a = __builtin_amdgcn_mfma_f32_16x16x32_f16(vp1, pf[nt][1], a, 0, 0, 0);
      a = __builtin_amdgcn_mfma_f32_16x16x32_f16(vp2, pf[nt][2], a, 0, 0, 0);
      a = __builtin_amdgcn_mfma_f32_16x16x32_f16(vp3, pf[nt][3], a, 0, 0, 0);
      acc[0][nt] = a;
    }
    #pragma unroll
    for (int dt = 1; dt < 4; ++dt) {
      const _Float16* vq = vp + (size_t)dt * 16 * N_;
      half8 v0 = *(const half8*)(vq);
      half8 v1 = *(const half8*)(vq + 32);
      half8 v2 = *(const half8*)(vq + 64);
      half8 v3 = *(const half8*)(vq + 96);
      #pragma unroll
      for (int nt = 0; nt < 2; ++nt) {
        f32x4 a = acc[dt][nt];
        a = __builtin_amdgcn_mfma_f32_16x16x32_f16(v0, pf[nt][0], a, 0, 0, 0);
        a = __builtin_amdgcn_mfma_f32_16x16x32_f16(v1, pf[nt][1], a, 0, 0, 0);
        a = __builtin_amdgcn_mfma_f32_16x16x32_f16(v2, pf[nt][2], a, 0, 0, 0);
        a = __builtin_amdgcn_mfma_f32_16x16x32_f16(v3, pf[nt][3], a, 0, 0, 0);
        acc[dt][nt] = a;
      }
    }
    __builtin_amdgcn_s_setprio(0);
  }

  // ---- Epilogue: out = gamma*acc + x   (1/l already folded into P)
  const float g = gamma[0];
  #pragma unroll
  for (int dt = 0; dt < 4; ++dt) {
    #pragma unroll
    for (int j = 0; j < 4; ++j) {
      const size_t row = ((size_t)b * C_ + d0 + dt * 16 + lh * 4 + j) * N_ + n0;
      out[row + ln]      = g * acc[dt][0][j] + x[row + ln];
      out[row + 16 + ln] = g * acc[dt][1][j] + x[row + 16 + ln];
    }
  }
}

extern "C" void kernel_launch(void* const* d_in, const int* in_sizes, int n_in,
                              void* d_out, int out_size, void* d_ws, size_t ws_size,
                              hipStream_t stream) {
  const float* x     = (const float*)d_in[0];
  const float* Wq    = (const float*)d_in[1];
  const float* Wk    = (const float*)d_in[2];
  const float* Wv    = (const float*)d_in[3];
  const float* gamma = (const float*)d_in[4];
  float* out = (float*)d_out;

  _Float16* Qh = (_Float16*)d_ws;                       // 2 MB
  _Float16* Kh = Qh + (size_t)B_ * N_ * CQ_;            // 2 MB
  _Float16* Vh = Kh + (size_t)B_ * N_ * CQ_;            // 16.8 MB
  float* m_g  = (float*)(Vh + (size_t)B_ * C_ * N_);    // 64 KB
  float* il_g = m_g + (size_t)B_ * N_;                  // 64 KB

  proj_kernel<<<dim3(64, 10, B_), 256, 0, stream>>>(x, Wq, Wk, Wv, Qh, Kh, Vh);
  stats_kernel<<<dim3(256), 256, 0, stream>>>(Qh, Kh, m_g, il_g);
  flashb_kernel<<<dim3(1024), 256, 0, stream>>>(x, Qh, Kh, Vh, m_g, il_g, gamma, out);
}

// Round 5
// 416.361 us; speedup vs baseline: 1.1429x; 1.1429x over previous
//
#include <hip/hip_runtime.h>

#define B_  4
#define C_  512
#define CQ_ 64
#define N_  4096
#define LOG2E 1.44269504088896f

typedef _Float16 half8 __attribute__((ext_vector_type(8)));
typedef float    f32x4 __attribute__((ext_vector_type(4)));

// ---------------------------------------------------------------------------
// Kernel 1: fused QKV projection.  Out(ch, n) = W(ch, c) * x(c, n) per batch.
// Q, K stored n-major: Qh[b][n][cq];  V stored d-major: Vh[b][d][m]
// ---------------------------------------------------------------------------
__global__ __launch_bounds__(256) void proj_kernel(
    const float* __restrict__ x,  const float* __restrict__ Wq,
    const float* __restrict__ Wk, const float* __restrict__ Wv,
    _Float16* __restrict__ Qh, _Float16* __restrict__ Kh, _Float16* __restrict__ Vh)
{
  __shared__ _Float16 As[64][40];
  __shared__ _Float16 Bs[64][40];

  const int tid = threadIdx.x;
  const int wid = tid >> 6, lane = tid & 63, ln = lane & 15, lh = lane >> 4;
  const int nBase  = blockIdx.x * 64;
  const int chTile = blockIdx.y;
  const int b      = blockIdx.z;

  const float* Wsrc;
  if (chTile == 0)      Wsrc = Wq;
  else if (chTile == 1) Wsrc = Wk;
  else                  Wsrc = Wv + (size_t)(chTile - 2) * 64 * C_;

  f32x4 acc[4] = {};

  const int ar = tid >> 2, ac = (tid & 3) * 8;
  const int bc = tid >> 3, bn = (tid & 7) * 8;

  for (int kt = 0; kt < C_; kt += 32) {
    __syncthreads();
    {
      const float* src = Wsrc + (size_t)ar * C_ + kt + ac;
      #pragma unroll
      for (int u = 0; u < 8; ++u) As[ar][ac + u] = (_Float16)src[u];
    }
    {
      const float* src = x + ((size_t)b * C_ + kt + bc) * N_ + nBase + bn;
      #pragma unroll
      for (int u = 0; u < 8; ++u) Bs[bn + u][bc] = (_Float16)src[u];
    }
    __syncthreads();
    half8 a = *(const half8*)&As[wid * 16 + ln][lh * 8];
    #pragma unroll
    for (int ct = 0; ct < 4; ++ct) {
      half8 bf = *(const half8*)&Bs[ct * 16 + ln][lh * 8];
      acc[ct] = __builtin_amdgcn_mfma_f32_16x16x32_f16(a, bf, acc[ct], 0, 0, 0);
    }
  }

  #pragma unroll
  for (int ct = 0; ct < 4; ++ct) {
    const int n = nBase + ct * 16 + ln;
    #pragma unroll
    for (int j = 0; j < 4; ++j) {
      const int chL = wid * 16 + lh * 4 + j;
      const _Float16 v = (_Float16)acc[ct][j];
      if (chTile == 0)      Qh[((size_t)b * N_ + n) * CQ_ + chL] = v;
      else if (chTile == 1) Kh[((size_t)b * N_ + n) * CQ_ + chL] = v;
      else                  Vh[((size_t)b * C_ + (chTile - 2) * 64 + chL) * N_ + n] = v;
    }
  }
}

// ---------------------------------------------------------------------------
// Kernel 2: attention, two fused passes.
// Block = (b, d-half, 32 query rows), 4 waves (256 thr); wave owns 64 d.
// Pass A: exact per-row max of E. Wave w scans keys {w*16 + it*64 + ln},
//         pure MFMA+max in registers, NO barriers, merged via LDS once.
// Pass B: per 64-key iter: E via MFMA -> P = exp2((e-m)*log2e) -> swizzled
//         fp16 LDS (double-buffered, ONE barrier/iter) -> PV MFMA.
//         l accumulated in registers (fixed row max => no rescale);
//         epilogue divides. K and V prefetched one iteration ahead.
// ---------------------------------------------------------------------------
__global__ __launch_bounds__(256) void attn_kernel(
    const float* __restrict__ x, const _Float16* __restrict__ Qh,
    const _Float16* __restrict__ Kh, const _Float16* __restrict__ Vh,
    const float* __restrict__ gamma, float* __restrict__ out)
{
  __shared__ _Float16 Ps[2][32][64];   // 8 KB, chunk-swizzled: phys = chunk ^ (n&7)
  __shared__ float    Mp[4][32];       // per-wave partial row maxes
  __shared__ float    Lp[4][32];       // per-wave partial softmax denominators

  const int tid = threadIdx.x;
  const int wid = tid >> 6, lane = tid & 63, ln = lane & 15, lh = lane >> 4;

  // bijective XCD swizzle: 1024 blocks; 128 consecutive wg (one b,d-half) per XCD
  const int wg = ((blockIdx.x & 7) << 7) + (blockIdx.x >> 3);
  const int b  = wg >> 8;
  const int dh = (wg >> 7) & 1;
  const int n0 = (wg & 127) * 32;
  const int d0w = dh * 256 + wid * 64;

  // persistent Q fragments (32 rows)
  half8 qf[2][2];
  #pragma unroll
  for (int rt = 0; rt < 2; ++rt)
    #pragma unroll
    for (int kk = 0; kk < 2; ++kk)
      qf[rt][kk] = *(const half8*)&Qh[((size_t)b * N_ + n0 + rt * 16 + ln) * CQ_ + kk * 32 + lh * 8];

  const _Float16* kp = Kh + ((size_t)b * N_ + (wid << 4) + ln) * CQ_ + (lh << 3);

  // ======== Pass A: exact per-row max (no barriers in the loop) ========
  float vmax[2][4] = {{-3.0e38f,-3.0e38f,-3.0e38f,-3.0e38f},
                      {-3.0e38f,-3.0e38f,-3.0e38f,-3.0e38f}};
  #pragma unroll 4
  for (int it = 0; it < 64; ++it) {
    const _Float16* kq = kp + (size_t)(it << 6) * CQ_;
    half8 k0 = *(const half8*)kq;
    half8 k1 = *(const half8*)(kq + 32);
    #pragma unroll
    for (int rt = 0; rt < 2; ++rt) {
      f32x4 e = {};
      e = __builtin_amdgcn_mfma_f32_16x16x32_f16(qf[rt][0], k0, e, 0, 0, 0);
      e = __builtin_amdgcn_mfma_f32_16x16x32_f16(qf[rt][1], k1, e, 0, 0, 0);
      #pragma unroll
      for (int j = 0; j < 4; ++j) vmax[rt][j] = fmaxf(vmax[rt][j], e[j]);
    }
  }
  #pragma unroll
  for (int rt = 0; rt < 2; ++rt)
    #pragma unroll
    for (int j = 0; j < 4; ++j) {
      float m = vmax[rt][j];
      m = fmaxf(m, __shfl_xor(m, 1));
      m = fmaxf(m, __shfl_xor(m, 2));
      m = fmaxf(m, __shfl_xor(m, 4));
      m = fmaxf(m, __shfl_xor(m, 8));
      if (ln == 0) Mp[wid][rt * 16 + lh * 4 + j] = m;
    }
  __syncthreads();

  // per-thread row-max (in log2 domain), for the rows this thread produces
  float mreg2[2][4];
  #pragma unroll
  for (int rt = 0; rt < 2; ++rt)
    #pragma unroll
    for (int j = 0; j < 4; ++j) {
      const int row = rt * 16 + lh * 4 + j;
      const float m = fmaxf(fmaxf(Mp[0][row], Mp[1][row]), fmaxf(Mp[2][row], Mp[3][row]));
      mreg2[rt][j] = m * LOG2E;
    }

  // ======== Pass B: P + PV pipeline ========
  half8 kf0 = *(const half8*)kp;
  half8 kf1 = *(const half8*)(kp + 32);

  const _Float16* vb = Vh + ((size_t)b * C_ + d0w + ln) * (size_t)N_ + (lh << 3);
  half8 vc[4][2];
  #pragma unroll
  for (int dt = 0; dt < 4; ++dt) {
    vc[dt][0] = *(const half8*)(vb + (size_t)dt * 16 * N_);
    vc[dt][1] = *(const half8*)(vb + (size_t)dt * 16 * N_ + 32);
  }

  f32x4 acc[4][2] = {};
  float lsum[2][4] = {};

  const int pchunk = (wid << 1) | (ln >> 3);   // P-store chunk index (key>>3)
  const int pcol   = ln & 7;

  for (int it = 0; it < 64; ++it) {
    const int m0  = it << 6;
    const int cur = it & 1;
    const int mn  = (m0 + 64) & (N_ - 1);      // wrapped prefetch offset

    // ---- Phase 1: prefetch next K; E = QK^T; P = exp2(e*log2e - m2) -> LDS
    half8 kn0 = *(const half8*)(kp + (size_t)mn * CQ_);
    half8 kn1 = *(const half8*)(kp + (size_t)mn * CQ_ + 32);

    #pragma unroll
    for (int rt = 0; rt < 2; ++rt) {
      f32x4 e = {};
      e = __builtin_amdgcn_mfma_f32_16x16x32_f16(qf[rt][0], kf0, e, 0, 0, 0);
      e = __builtin_amdgcn_mfma_f32_16x16x32_f16(qf[rt][1], kf1, e, 0, 0, 0);
      #pragma unroll
      for (int j = 0; j < 4; ++j) {
        const float p = exp2f(fmaf(e[j], LOG2E, -mreg2[rt][j]));
        lsum[rt][j] += p;
        const int n = rt * 16 + lh * 4 + j;
        Ps[cur][n][((pchunk ^ (n & 7)) << 3) | pcol] = (_Float16)p;
      }
    }
    kf0 = kn0; kf1 = kn1;
    __syncthreads();

    // ---- Phase 2: pf from LDS; prefetch next V inside dt loop; PV MFMA
    half8 pf[2][2];
    const int sw = ln & 7;
    #pragma unroll
    for (int nt = 0; nt < 2; ++nt)
      #pragma unroll
      for (int q = 0; q < 2; ++q)
        pf[nt][q] = *(const half8*)&Ps[cur][nt * 16 + ln][((((q << 2) | lh) ^ sw) << 3)];

    __builtin_amdgcn_s_setprio(1);
    #pragma unroll
    for (int dt = 0; dt < 4; ++dt) {
      half8 vn0 = *(const half8*)(vb + (size_t)dt * 16 * N_ + mn);
      half8 vn1 = *(const half8*)(vb + (size_t)dt * 16 * N_ + mn + 32);
      #pragma unroll
      for (int nt = 0; nt < 2; ++nt) {
        f32x4 a = acc[dt][nt];
        a = __builtin_amdgcn_mfma_f32_16x16x32_f16(vc[dt][0], pf[nt][0], a, 0, 0, 0);
        a = __builtin_amdgcn_mfma_f32_16x16x32_f16(vc[dt][1], pf[nt][1], a, 0, 0, 0);
        acc[dt][nt] = a;
      }
      vc[dt][0] = vn0; vc[dt][1] = vn1;
    }
    __builtin_amdgcn_s_setprio(0);
  }

  // ---- reduce l across the 16 key-lanes, then across the 4 waves via LDS
  #pragma unroll
  for (int rt = 0; rt < 2; ++rt)
    #pragma unroll
    for (int j = 0; j < 4; ++j) {
      float s = lsum[rt][j];
      s += __shfl_xor(s, 1);
      s += __shfl_xor(s, 2);
      s += __shfl_xor(s, 4);
      s += __shfl_xor(s, 8);
      if (ln == 0) Lp[wid][rt * 16 + lh * 4 + j] = s;
    }
  __syncthreads();

  float linv[2];
  #pragma unroll
  for (int nt = 0; nt < 2; ++nt) {
    const int n = nt * 16 + ln;
    linv[nt] = 1.0f / (Lp[0][n] + Lp[1][n] + Lp[2][n] + Lp[3][n]);
  }

  const float g = gamma[0];
  #pragma unroll
  for (int dt = 0; dt < 4; ++dt) {
    #pragma unroll
    for (int j = 0; j < 4; ++j) {
      const size_t row = ((size_t)b * C_ + d0w + dt * 16 + lh * 4 + j) * N_ + n0;
      out[row + ln]      = g * acc[dt][0][j] * linv[0] + x[row + ln];
      out[row + 16 + ln] = g * acc[dt][1][j] * linv[1] + x[row + 16 + ln];
    }
  }
}

extern "C" void kernel_launch(void* const* d_in, const int* in_sizes, int n_in,
                              void* d_out, int out_size, void* d_ws, size_t ws_size,
                              hipStream_t stream) {
  const float* x     = (const float*)d_in[0];
  const float* Wq    = (const float*)d_in[1];
  const float* Wk    = (const float*)d_in[2];
  const float* Wv    = (const float*)d_in[3];
  const float* gamma = (const float*)d_in[4];
  float* out = (float*)d_out;

  _Float16* Qh = (_Float16*)d_ws;                       // 2 MB
  _Float16* Kh = Qh + (size_t)B_ * N_ * CQ_;            // 2 MB
  _Float16* Vh = Kh + (size_t)B_ * N_ * CQ_;            // 16.8 MB

  proj_kernel<<<dim3(64, 10, B_), 256, 0, stream>>>(x, Wq, Wk, Wv, Qh, Kh, Vh);
  attn_kernel<<<dim3(1024), 256, 0, stream>>>(x, Qh, Kh, Vh, gamma, out);
}